// Round 8
// baseline (863.925 us; speedup 1.0000x reference)
//
#include <hip/hip_runtime.h>

// ---------------------------------------------------------------------------
// GCN (2-branch) + GAP + MLP head, MI355X.
// R7: dual-branch merged launches (L+S in one grid per stage) — dispatch count
// 45 -> ~19, S-branch rides in L-branch occupancy gaps; aggregate edge unroll
// deepened to 8 (more outstanding gathers/wave). Numerics identical to R6.
// ---------------------------------------------------------------------------

static inline size_t align256(size_t x) { return (x + 255) & ~size_t(255); }

__device__ inline unsigned short f2bf(float f) {  // RNE fp32 -> bf16
    unsigned u = __float_as_uint(f);
    unsigned r = (u + 0x7fffu + ((u >> 16) & 1u)) >> 16;
    return (unsigned short)r;
}
__device__ inline unsigned packbf2(float lo, float hi) {
    return (unsigned)f2bf(lo) | ((unsigned)f2bf(hi) << 16);
}

typedef __attribute__((ext_vector_type(8))) short short8;
typedef __attribute__((ext_vector_type(4))) float floatx4;

#define CHUNK 4096  // edges per block in P0/P2

// ---------------- P0: bucket histogram (bucket = dst>>8), dual ----------------
__global__ __launch_bounds__(256) void bucket_hist_dual(
    const int* __restrict__ dstL, int EL, int NBL, int* __restrict__ bhL,
    const int* __restrict__ dstS, int ES, int NBS, int* __restrict__ bhS, int CL) {
    __shared__ int hist[512];
    int b = blockIdx.x, t = threadIdx.x;
    const int* dst; int E, NB, blk; int* bh;
    if (b < CL) { dst = dstL; E = EL; NB = NBL; bh = bhL; blk = b; }
    else        { dst = dstS; E = ES; NB = NBS; bh = bhS; blk = b - CL; }
    for (int i = t; i < NB; i += 256) hist[i] = 0;
    __syncthreads();
    int base = blk * CHUNK;
    int end = min(E, base + CHUNK);
    for (int e = base + t; e < end; e += 256) atomicAdd(&hist[dst[e] >> 8], 1);
    __syncthreads();
    for (int i = t; i < NB; i += 256) {
        int h = hist[i];
        if (h > 0) atomicAdd(&bh[i], h);
    }
}

// ---------------- P1: scan bucket totals (2 blocks: L then S) ----------------
__global__ __launch_bounds__(256) void scan_buckets_dual(
    const int* __restrict__ bhist, int* __restrict__ bbase, int* __restrict__ bcur,
    int nbL, int* __restrict__ rpL, int NL, int EL,
    int nbS, int* __restrict__ rpS, int NS, int ES) {
    __shared__ int wsum[4];
    int which = blockIdx.x, t = threadIdx.x;
    const int* bh = bhist + which * 512;
    int* bb = bbase + which * 512;
    int* bc = bcur + which * 512;
    int nb = which ? nbS : nbL;
    int* rp = which ? rpS : rpL;
    int N = which ? NS : NL;
    int E = which ? ES : EL;
    int wave = t >> 6, lane = t & 63;
    int i0 = 2 * t, i1 = 2 * t + 1;
    int v0 = (i0 < nb) ? bh[i0] : 0;
    int v1 = (i1 < nb) ? bh[i1] : 0;
    int tsum = v0 + v1;
    int x = tsum;
    #pragma unroll
    for (int off = 1; off < 64; off <<= 1) {
        int y = __shfl_up(x, off, 64);
        if (lane >= off) x += y;
    }
    if (lane == 63) wsum[wave] = x;
    __syncthreads();
    int woff = 0;
    #pragma unroll
    for (int i = 0; i < 3; i++) if (wave > i) woff += wsum[i];
    int texcl = woff + x - tsum;
    if (i0 < nb) { bb[i0] = texcl; bc[i0] = texcl; }
    if (i1 < nb) { bb[i1] = texcl + v0; bc[i1] = texcl + v0; }
    if (t == 255) { bb[nb] = woff + x; rp[N] = E; }
}

// ---------------- P2: partition edges into bucket regions, dual ----------------
__global__ __launch_bounds__(256) void partition_edges_dual(
    const int* __restrict__ srcL, const int* __restrict__ dstL,
    const float* __restrict__ wL, int EL, int NBL, int* __restrict__ bcurL,
    int2* __restrict__ partL,
    const int* __restrict__ srcS, const int* __restrict__ dstS,
    const float* __restrict__ wS, int ES, int NBS, int* __restrict__ bcurS,
    int2* __restrict__ partS, int CL) {
    __shared__ int hist[512];
    __shared__ int lcur[512];
    int b = blockIdx.x, t = threadIdx.x;
    const int *src, *dst; const float* w; int E, NB, blk; int* bcur; int2* part;
    if (b < CL) { src = srcL; dst = dstL; w = wL; E = EL; NB = NBL; bcur = bcurL;
                  part = partL; blk = b; }
    else        { src = srcS; dst = dstS; w = wS; E = ES; NB = NBS; bcur = bcurS;
                  part = partS; blk = b - CL; }
    for (int i = t; i < NB; i += 256) hist[i] = 0;
    __syncthreads();
    int base = blk * CHUNK;
    int end = min(E, base + CHUNK);
    for (int e = base + t; e < end; e += 256) atomicAdd(&hist[dst[e] >> 8], 1);
    __syncthreads();
    for (int i = t; i < NB; i += 256) {
        int h = hist[i];
        if (h > 0) lcur[i] = atomicAdd(&bcur[i], h);
    }
    __syncthreads();
    for (int e = base + t; e < end; e += 256) {
        int d = dst[e];
        int bk = d >> 8;
        int pos = atomicAdd(&lcur[bk], 1);
        part[pos] = make_int2(src[e] | ((d & 255) << 24), __float_as_int(w[e]));
    }
}

// ---------------- P3: per-bucket CSR + rp + dinv, dual ----------------
__global__ __launch_bounds__(256) void bucket_csr_dual(
    const int2* __restrict__ partL, const int* __restrict__ bbaseL, int NL,
    int* __restrict__ rpL, float* __restrict__ dinvL, int2* __restrict__ csrL,
    const int2* __restrict__ partS, const int* __restrict__ bbaseS, int NS,
    int* __restrict__ rpS, float* __restrict__ dinvS, int2* __restrict__ csrS,
    int NBL) {
    __shared__ int hist[256];
    __shared__ float degw[256];
    __shared__ int wsum[4];
    int bb = blockIdx.x, t = threadIdx.x;
    const int2* part; const int* bbase; int N, b; int* rp; float* dinv; int2* csr;
    if (bb < NBL) { part = partL; bbase = bbaseL; N = NL; rp = rpL; dinv = dinvL;
                    csr = csrL; b = bb; }
    else          { part = partS; bbase = bbaseS; N = NS; rp = rpS; dinv = dinvS;
                    csr = csrS; b = bb - NBL; }
    int node0 = b << 8;
    int nn = min(256, N - node0);
    int ebase = bbase[b], eend = bbase[b + 1];
    hist[t] = 0;
    degw[t] = 0.f;
    __syncthreads();
    for (int e = ebase + t; e < eend; e += 256) {
        int2 rec = part[e];
        int nloc = ((unsigned)rec.x) >> 24;
        atomicAdd(&hist[nloc], 1);
        atomicAdd(&degw[nloc], __int_as_float(rec.y));
    }
    __syncthreads();
    int v = hist[t];
    int x = v;
    int wave = t >> 6, lane = t & 63;
    #pragma unroll
    for (int off = 1; off < 64; off <<= 1) {
        int y = __shfl_up(x, off, 64);
        if (lane >= off) x += y;
    }
    if (lane == 63) wsum[wave] = x;
    __syncthreads();
    int woff = 0;
    #pragma unroll
    for (int i = 0; i < 3; i++) if (wave > i) woff += wsum[i];
    int excl = woff + x - v;
    if (t < nn) {
        rp[node0 + t] = ebase + excl;
        dinv[node0 + t] = rsqrtf(1.f + degw[t]);
    }
    hist[t] = excl;
    __syncthreads();
    for (int e = ebase + t; e < eend; e += 256) {
        int2 rec = part[e];
        int nloc = ((unsigned)rec.x) >> 24;
        int pos = ebase + atomicAdd(&hist[nloc], 1);
        csr[pos] = make_int2(rec.x & 0x00FFFFFF, rec.y);
    }
}

// ---------------- layer-0 cast (dual): h~ = bf16(dinv[node] * x) ----------------
template <int F8>
__device__ void cast_body(const float* __restrict__ in, size_t n8,
                          const float* __restrict__ dinv,
                          unsigned short* __restrict__ out, size_t i) {
    if (i >= n8) return;
    float s = dinv[i / F8];
    const float4* in4 = (const float4*)in;
    float4 a = in4[i * 2], b = in4[i * 2 + 1];
    ushort4 lo, hi;
    lo.x = f2bf(a.x * s); lo.y = f2bf(a.y * s); lo.z = f2bf(a.z * s); lo.w = f2bf(a.w * s);
    hi.x = f2bf(b.x * s); hi.y = f2bf(b.y * s); hi.z = f2bf(b.z * s); hi.w = f2bf(b.w * s);
    ushort4* o4 = (ushort4*)out;
    o4[i * 2] = lo;
    o4[i * 2 + 1] = hi;
}

__global__ void cast0_dual(const float* __restrict__ xL, size_t n8L,
                           const float* __restrict__ dinvL, unsigned short* __restrict__ oL,
                           const float* __restrict__ xS, size_t n8S,
                           const float* __restrict__ dinvS, unsigned short* __restrict__ oS,
                           int BL) {
    int b = blockIdx.x;
    if (b < BL) cast_body<8>(xL, n8L, dinvL, oL, (size_t)b * 256 + threadIdx.x);
    else        cast_body<4>(xS, n8S, dinvS, oS, (size_t)(b - BL) * 256 + threadIdx.x);
}

// ---------------- weight cast + transpose ----------------
struct WCastArgs {
    const float* w[8];
    unsigned short* o[8];
    int K[8];
};
__global__ void cast_w16t(WCastArgs p) {
    int mi = blockIdx.y;
    int K = p.K[mi];
    int id = blockIdx.x * 256 + threadIdx.x;
    if (id >= K * 128) return;
    int k = id >> 7, c = id & 127;
    p.o[mi][c * K + k] = f2bf(p.w[mi][k * 128 + c]);
}

// ---------------- aggregation body: z = bf16(dinv[n]*(sum w*h~[src] + h~[n])) ----
template <int LANES>
__device__ void agg_body(const unsigned short* __restrict__ h16, int N,
                         const int* __restrict__ rp, const int2* __restrict__ csr,
                         const float* __restrict__ dinv,
                         unsigned short* __restrict__ z16, int blk) {
    constexpr int GPB = 256 / LANES;
    int group = threadIdx.x / LANES;
    int lane = threadIdx.x % LANES;
    int n = blk * GPB + group;
    if (n >= N) return;
    const uint4* h4 = (const uint4*)h16;
    float acc[8];
    #pragma unroll
    for (int i = 0; i < 8; i++) acc[i] = 0.f;

    int e = rp[n], end = rp[n + 1];
    #define ACC8(q, nm)                                                   \
    {                                                                     \
        acc[0] += nm * __uint_as_float(q.x << 16);                        \
        acc[1] += nm * __uint_as_float(q.x & 0xffff0000u);                \
        acc[2] += nm * __uint_as_float(q.y << 16);                        \
        acc[3] += nm * __uint_as_float(q.y & 0xffff0000u);                \
        acc[4] += nm * __uint_as_float(q.z << 16);                        \
        acc[5] += nm * __uint_as_float(q.z & 0xffff0000u);                \
        acc[6] += nm * __uint_as_float(q.w << 16);                        \
        acc[7] += nm * __uint_as_float(q.w & 0xffff0000u);                \
    }
    for (; e + 7 < end; e += 8) {
        int2 c[8];
        uint4 q[8];
        #pragma unroll
        for (int j = 0; j < 8; j++) c[j] = csr[e + j];
        #pragma unroll
        for (int j = 0; j < 8; j++) q[j] = h4[(size_t)c[j].x * LANES + lane];
        #pragma unroll
        for (int j = 0; j < 8; j++) {
            float nm = __int_as_float(c[j].y);
            ACC8(q[j], nm)
        }
    }
    for (; e + 3 < end; e += 4) {
        int2 c[4];
        uint4 q[4];
        #pragma unroll
        for (int j = 0; j < 4; j++) c[j] = csr[e + j];
        #pragma unroll
        for (int j = 0; j < 4; j++) q[j] = h4[(size_t)c[j].x * LANES + lane];
        #pragma unroll
        for (int j = 0; j < 4; j++) {
            float nm = __int_as_float(c[j].y);
            ACC8(q[j], nm)
        }
    }
    for (; e < end; e++) {
        int2 c = csr[e];
        uint4 q = h4[(size_t)c.x * LANES + lane];
        float nm = __int_as_float(c.y);
        ACC8(q, nm)
    }
    uint4 qs = h4[(size_t)n * LANES + lane];
    float di = dinv[n];
    float v0 = (acc[0] + __uint_as_float(qs.x << 16)) * di;
    float v1 = (acc[1] + __uint_as_float(qs.x & 0xffff0000u)) * di;
    float v2 = (acc[2] + __uint_as_float(qs.y << 16)) * di;
    float v3 = (acc[3] + __uint_as_float(qs.y & 0xffff0000u)) * di;
    float v4 = (acc[4] + __uint_as_float(qs.z << 16)) * di;
    float v5 = (acc[5] + __uint_as_float(qs.z & 0xffff0000u)) * di;
    float v6 = (acc[6] + __uint_as_float(qs.w << 16)) * di;
    float v7 = (acc[7] + __uint_as_float(qs.w & 0xffff0000u)) * di;
    uint4 o;
    o.x = packbf2(v0, v1); o.y = packbf2(v2, v3);
    o.z = packbf2(v4, v5); o.w = packbf2(v6, v7);
    *(uint4*)&z16[(size_t)n * (LANES * 8) + lane * 8] = o;
    #undef ACC8
}

// layer 1-3: both branches F=128 (LANES=16)
__global__ __launch_bounds__(256) void aggregate_dual(
    const unsigned short* __restrict__ hL, int NL, const int* __restrict__ rpL,
    const int2* __restrict__ csrL, const float* __restrict__ dinvL,
    unsigned short* __restrict__ zL,
    const unsigned short* __restrict__ hS, int NS, const int* __restrict__ rpS,
    const int2* __restrict__ csrS, const float* __restrict__ dinvS,
    unsigned short* __restrict__ zS, int gL) {
    int b = blockIdx.x;
    if (b < gL) agg_body<16>(hL, NL, rpL, csrL, dinvL, zL, b);
    else        agg_body<16>(hS, NS, rpS, csrS, dinvS, zS, b - gL);
}

// layer 0: L F=64 (LANES=8), S F=32 (LANES=4)
__global__ __launch_bounds__(256) void aggregate0_dual(
    const unsigned short* __restrict__ hL, int NL, const int* __restrict__ rpL,
    const int2* __restrict__ csrL, const float* __restrict__ dinvL,
    unsigned short* __restrict__ zL,
    const unsigned short* __restrict__ hS, int NS, const int* __restrict__ rpS,
    const int2* __restrict__ csrS, const float* __restrict__ dinvS,
    unsigned short* __restrict__ zS, int gL) {
    int b = blockIdx.x;
    if (b < gL) agg_body<8>(hL, NL, rpL, csrL, dinvL, zL, b);
    else        agg_body<4>(hS, NS, rpS, csrS, dinvS, zS, b - gL);
}

// ---------------- MFMA GEMM body ----------------
template <int K>
__device__ void gemm_body(const unsigned short* __restrict__ Z16,
                          const unsigned short* __restrict__ WT16,
                          const float* __restrict__ bias, const float* __restrict__ dinv,
                          float* __restrict__ Hf, unsigned short* __restrict__ H16,
                          int N, int blk, unsigned short* WT) {
    constexpr int KP = K + 8;
    int tid = threadIdx.x;
    constexpr int CH = 128 * K / 8;
    for (int i = tid; i < CH; i += 256) {
        int c = i / (K / 8), kc = i % (K / 8);
        *(uint4*)&WT[c * KP + kc * 8] = *(const uint4*)&WT16[c * K + kc * 8];
    }
    __syncthreads();

    int wave = tid >> 6, lane = tid & 63;
    int m = lane & 15, quad = lane >> 4;
    int rowbase = blk * 128 + wave * 32;

    floatx4 acc[2][8];
    #pragma unroll
    for (int t = 0; t < 2; t++)
        #pragma unroll
        for (int ct = 0; ct < 8; ct++) acc[t][ct] = (floatx4)0.f;

    for (int ks = 0; ks < K; ks += 32) {
        short8 a[2];
        #pragma unroll
        for (int t = 0; t < 2; t++) {
            int r = rowbase + t * 16 + m;
            short8 av = (short8)0;
            if (r < N) av = *(const short8*)&Z16[(size_t)r * K + ks + quad * 8];
            a[t] = av;
        }
        #pragma unroll
        for (int ct = 0; ct < 8; ct++) {
            short8 b = *(const short8*)&WT[(ct * 16 + m) * KP + ks + quad * 8];
            acc[0][ct] = __builtin_amdgcn_mfma_f32_16x16x32_bf16(a[0], b, acc[0][ct], 0, 0, 0);
            acc[1][ct] = __builtin_amdgcn_mfma_f32_16x16x32_bf16(a[1], b, acc[1][ct], 0, 0, 0);
        }
    }

    float bv[8];
    #pragma unroll
    for (int ct = 0; ct < 8; ct++) bv[ct] = bias[ct * 16 + m];

    #pragma unroll
    for (int t = 0; t < 2; t++) {
        #pragma unroll
        for (int reg = 0; reg < 4; reg++) {
            int r = rowbase + t * 16 + quad * 4 + reg;
            if (r >= N) continue;
            float di = H16 ? dinv[r] : 1.f;
            #pragma unroll
            for (int ct = 0; ct < 8; ct++) {
                float o = fmaxf(acc[t][ct][reg] + bv[ct], 0.f);
                size_t off = (size_t)r * 128 + ct * 16 + m;
                if (H16) H16[off] = f2bf(o * di);
                if (Hf) Hf[off] = o;
            }
        }
    }
}

template <int K>
__global__ __launch_bounds__(256) void gemm_mfma(
    const unsigned short* __restrict__ Z16, const unsigned short* __restrict__ WT16,
    const float* __restrict__ bias, const float* __restrict__ dinv,
    float* __restrict__ Hf, unsigned short* __restrict__ H16, int N) {
    __shared__ __attribute__((aligned(16))) unsigned short WT[128 * (K + 8)];
    gemm_body<K>(Z16, WT16, bias, dinv, Hf, H16, N, blockIdx.x, WT);
}

__global__ __launch_bounds__(256) void gemm_mfma_dual128(
    const unsigned short* __restrict__ ZL, const unsigned short* __restrict__ WTL,
    const float* __restrict__ bL, const float* __restrict__ dinvL,
    float* __restrict__ HfL, unsigned short* __restrict__ H16L, int NL,
    const unsigned short* __restrict__ ZS, const unsigned short* __restrict__ WTS,
    const float* __restrict__ bS, const float* __restrict__ dinvS,
    float* __restrict__ HfS, unsigned short* __restrict__ H16S, int NS, int gmL) {
    __shared__ __attribute__((aligned(16))) unsigned short WT[128 * 136];
    int b = blockIdx.x;
    if (b < gmL) gemm_body<128>(ZL, WTL, bL, dinvL, HfL, H16L, NL, b, WT);
    else         gemm_body<128>(ZS, WTS, bS, dinvS, HfS, H16S, NS, b - gmL, WT);
}

// ---------------- pooling (dual): run-length segment accumulation ----------------
__device__ void pool_body(const float* __restrict__ h, const int* __restrict__ batch,
                          int N, float* __restrict__ psum, int blk) {
    int tid = threadIdx.x;
    int f4 = tid & 31;
    int nl = tid >> 5;
    int n0 = blk * 256 + nl;
    const float4* h4 = (const float4*)h;
    float4 acc = make_float4(0.f, 0.f, 0.f, 0.f);
    int cur = -1;
    #pragma unroll 4
    for (int i = 0; i < 32; i++) {
        int n = n0 + i * 8;
        if (n >= N) break;
        int g = batch[n];
        if (g != cur) {
            if (cur >= 0) {
                float* d = &psum[(size_t)cur * 128 + f4 * 4];
                atomicAdd(d + 0, acc.x);
                atomicAdd(d + 1, acc.y);
                atomicAdd(d + 2, acc.z);
                atomicAdd(d + 3, acc.w);
            }
            cur = g;
            acc = make_float4(0.f, 0.f, 0.f, 0.f);
        }
        float4 v = h4[(size_t)n * 32 + f4];
        acc.x += v.x; acc.y += v.y; acc.z += v.z; acc.w += v.w;
    }
    if (cur >= 0) {
        float* d = &psum[(size_t)cur * 128 + f4 * 4];
        atomicAdd(d + 0, acc.x);
        atomicAdd(d + 1, acc.y);
        atomicAdd(d + 2, acc.z);
        atomicAdd(d + 3, acc.w);
    }
}

__global__ __launch_bounds__(256) void pool_dual(
    const float* __restrict__ hL, const int* __restrict__ bL, int NL,
    const float* __restrict__ hS, const int* __restrict__ bS, int NS,
    float* __restrict__ psum, int gL) {
    int b = blockIdx.x;
    if (b < gL) pool_body(hL, bL, NL, psum, b);
    else        pool_body(hS, bS, NS, psum, b - gL);
}

// ---------------- MLP head ----------------
__device__ inline int lower_bound(const int* __restrict__ a, int n, int v) {
    int lo = 0, hi = n;
    while (lo < hi) {
        int m = (lo + hi) >> 1;
        if (a[m] < v) lo = m + 1; else hi = m;
    }
    return lo;
}

__global__ void mlp_kernel(const float* __restrict__ psum,
                           const int* __restrict__ batchL, int NL,
                           const int* __restrict__ batchS, int NS,
                           const float* __restrict__ W1, const float* __restrict__ b1,
                           const float* __restrict__ W2, const float* __restrict__ b2,
                           const float* __restrict__ gamma, const float* __restrict__ beta,
                           const float* __restrict__ outW, const float* __restrict__ outb,
                           float* __restrict__ d_out) {
    __shared__ float row[128];
    __shared__ float row2[128];
    int g = blockIdx.x, t = threadIdx.x;  // 128 threads
    int cnt = (lower_bound(batchL, NL, g + 1) - lower_bound(batchL, NL, g)) +
              (lower_bound(batchS, NS, g + 1) - lower_bound(batchS, NS, g));
    float rcp = 1.f / (float)(cnt > 0 ? cnt : 1);
    row[t] = psum[(size_t)g * 128 + t] * rcp;
    __syncthreads();
    float a = b1[t];
    #pragma unroll 4
    for (int k = 0; k < 128; k++) a += row[k] * W1[k * 128 + t];
    row2[t] = a;  // no relu between lin1 and lin2 in reference
    __syncthreads();
    if (t < 64) {
        float a2 = b2[t];
        #pragma unroll 4
        for (int k = 0; k < 128; k++) a2 += row2[k] * W2[k * 64 + t];
        float rs = rsqrtf(1.0f + 1e-5f);
        float hb = a2 * rs * gamma[t] + beta[t];
        float hr = fmaxf(hb, 0.f);
        d_out[512 + g * 64 + t] = hr;
        float p = hr * outW[t];
        #pragma unroll
        for (int off = 32; off > 0; off >>= 1) p += __shfl_down(p, off, 64);
        if (t == 0) d_out[g] = p + outb[0];
    }
}

// ---------------------------------------------------------------------------
extern "C" void kernel_launch(void* const* d_in, const int* in_sizes, int n_in,
                              void* d_out, int out_size, void* d_ws, size_t ws_size,
                              hipStream_t stream) {
    const float* x_l = (const float*)d_in[0];
    const int*   ei_l = (const int*)d_in[1];
    const float* w_l = (const float*)d_in[2];
    const float* x_s = (const float*)d_in[3];
    const int*   ei_s = (const int*)d_in[4];
    const float* w_s = (const float*)d_in[5];
    const int*   batch_l = (const int*)d_in[6];
    const int*   batch_s = (const int*)d_in[7];

    const int NL = in_sizes[6];           // 100000
    const int NS = in_sizes[7];           // 50000
    const int EL = in_sizes[2];           // 1600000
    const int ES = in_sizes[5];           // 800000

    const float* Wa[4] = {(const float*)d_in[8],  (const float*)d_in[12],
                          (const float*)d_in[16], (const float*)d_in[20]};
    const float* ba[4] = {(const float*)d_in[9],  (const float*)d_in[13],
                          (const float*)d_in[17], (const float*)d_in[21]};
    const float* Wb[4] = {(const float*)d_in[10], (const float*)d_in[14],
                          (const float*)d_in[18], (const float*)d_in[22]};
    const float* bb[4] = {(const float*)d_in[11], (const float*)d_in[15],
                          (const float*)d_in[19], (const float*)d_in[23]};
    const float* lin1_W = (const float*)d_in[24];
    const float* lin1_b = (const float*)d_in[25];
    const float* lin2_W = (const float*)d_in[26];
    const float* lin2_b = (const float*)d_in[27];
    const float* bn_g = (const float*)d_in[28];
    const float* bn_b = (const float*)d_in[29];
    const float* out_W = (const float*)d_in[30];
    const float* out_b = (const float*)d_in[31];
    float* out = (float*)d_out;

    const int* src_l = ei_l;
    const int* dst_l = ei_l + EL;
    const int* src_s = ei_s;
    const int* dst_s = ei_s + ES;

    const int NBL = (NL + 255) >> 8;  // 391
    const int NBS = (NS + 255) >> 8;  // 196
    const int CL = (EL + CHUNK - 1) / CHUNK;
    const int CS = (ES + CHUNK - 1) / CHUNK;

    // ---- workspace carve ----
    char* p = (char*)d_ws;
    auto alloc = [&](size_t bytes) { char* r = p; p += align256(bytes); return r; };
    float* A_l = (float*)alloc((size_t)NL * 128 * 4);   // final-layer fp32 acts
    float* A_s = (float*)alloc((size_t)NS * 128 * 4);
    unsigned short* Z16_l = (unsigned short*)alloc((size_t)NL * 128 * 2);
    unsigned short* Z16_s = (unsigned short*)alloc((size_t)NS * 128 * 2);
    unsigned short* H16_l = (unsigned short*)alloc((size_t)NL * 128 * 2);
    unsigned short* H16_s = (unsigned short*)alloc((size_t)NS * 128 * 2);
    int2*  csr_l  = (int2*)alloc((size_t)EL * 8);
    int2*  csr_s  = (int2*)alloc((size_t)ES * 8);
    int2*  part_l = (int2*)alloc((size_t)EL * 8);
    int2*  part_s = (int2*)alloc((size_t)ES * 8);
    int*   rp_l  = (int*)alloc((size_t)(NL + 1) * 4);
    int*   rp_s  = (int*)alloc((size_t)(NS + 1) * 4);
    float* dinv_l = (float*)alloc((size_t)NL * 4);
    float* dinv_s = (float*)alloc((size_t)NS * 4);
    int*   bhist  = (int*)alloc(1024 * 4);   // [0..511] L, [512..1023] S
    int*   bbase  = (int*)alloc(1024 * 4);
    int*   bcur   = (int*)alloc(1024 * 4);
    float* psum = (float*)alloc((size_t)512 * 128 * 4);
    unsigned short* WTa[4];
    unsigned short* WTb[4];
    WTa[0] = (unsigned short*)alloc((size_t)128 * 64 * 2);
    for (int i = 1; i < 4; i++) WTa[i] = (unsigned short*)alloc((size_t)128 * 128 * 2);
    WTb[0] = (unsigned short*)alloc((size_t)128 * 32 * 2);
    for (int i = 1; i < 4; i++) WTb[i] = (unsigned short*)alloc((size_t)128 * 128 * 2);
    (void)ws_size; (void)n_in; (void)out_size;

    // ---- zero init ----
    hipMemsetAsync(bhist, 0, 1024 * 4, stream);
    hipMemsetAsync(psum, 0, (size_t)512 * 128 * 4, stream);

    // ---- weight cast+transpose ----
    {
        WCastArgs wa;
        for (int i = 0; i < 4; i++) {
            wa.w[i] = Wa[i]; wa.o[i] = WTa[i]; wa.K[i] = (i == 0) ? 64 : 128;
            wa.w[4 + i] = Wb[i]; wa.o[4 + i] = WTb[i]; wa.K[4 + i] = (i == 0) ? 32 : 128;
        }
        cast_w16t<<<dim3(64, 8), 256, 0, stream>>>(wa);
    }

    // ---- CSR build (dual) ----
    bucket_hist_dual<<<CL + CS, 256, 0, stream>>>(dst_l, EL, NBL, bhist,
                                                  dst_s, ES, NBS, bhist + 512, CL);
    scan_buckets_dual<<<2, 256, 0, stream>>>(bhist, bbase, bcur,
                                             NBL, rp_l, NL, EL,
                                             NBS, rp_s, NS, ES);
    partition_edges_dual<<<CL + CS, 256, 0, stream>>>(
        src_l, dst_l, w_l, EL, NBL, bcur, part_l,
        src_s, dst_s, w_s, ES, NBS, bcur + 512, part_s, CL);
    bucket_csr_dual<<<NBL + NBS, 256, 0, stream>>>(
        part_l, bbase, NL, rp_l, dinv_l, csr_l,
        part_s, bbase + 512, NS, rp_s, dinv_s, csr_s, NBL);

    // ---- layer-0 casts (dual) ----
    const size_t n8l = (size_t)NL * 8;   // 64 feats / 8
    const size_t n8s = (size_t)NS * 4;   // 32 feats / 8
    const int cBL = (int)((n8l + 255) / 256);
    const int cBS = (int)((n8s + 255) / 256);
    cast0_dual<<<cBL + cBS, 256, 0, stream>>>(x_l, n8l, dinv_l, H16_l,
                                              x_s, n8s, dinv_s, H16_s, cBL);

    const int gmL = (NL + 127) / 128;
    const int gmS = (NS + 127) / 128;
    const int aL = (NL + 15) / 16;   // LANES=16 blocks
    const int aS = (NS + 15) / 16;
    const int a0L = (NL + 31) / 32;  // LANES=8 blocks
    const int a0S = (NS + 63) / 64;  // LANES=4 blocks

    // ---- layer 0 ----
    aggregate0_dual<<<a0L + a0S, 256, 0, stream>>>(
        H16_l, NL, rp_l, csr_l, dinv_l, Z16_l,
        H16_s, NS, rp_s, csr_s, dinv_s, Z16_s, a0L);
    gemm_mfma<64><<<gmL, 256, 0, stream>>>(Z16_l, WTa[0], ba[0], dinv_l,
                                           (float*)nullptr, H16_l, NL);
    gemm_mfma<32><<<gmS, 256, 0, stream>>>(Z16_s, WTb[0], bb[0], dinv_s,
                                           (float*)nullptr, H16_s, NS);

    // ---- layers 1-3 (dual) ----
    for (int layer = 1; layer < 4; layer++) {
        aggregate_dual<<<aL + aS, 256, 0, stream>>>(
            H16_l, NL, rp_l, csr_l, dinv_l, Z16_l,
            H16_s, NS, rp_s, csr_s, dinv_s, Z16_s, aL);
        if (layer < 3)
            gemm_mfma_dual128<<<gmL + gmS, 256, 0, stream>>>(
                Z16_l, WTa[layer], ba[layer], dinv_l, (float*)nullptr, H16_l, NL,
                Z16_s, WTb[layer], bb[layer], dinv_s, (float*)nullptr, H16_s, NS, gmL);
        else
            gemm_mfma_dual128<<<gmL + gmS, 256, 0, stream>>>(
                Z16_l, WTa[layer], ba[layer], dinv_l, A_l, (unsigned short*)nullptr, NL,
                Z16_s, WTb[layer], bb[layer], dinv_s, A_s, (unsigned short*)nullptr, NS, gmL);
    }

    // ---- pooling + head ----
    const int pL = (NL + 255) / 256;
    const int pS = (NS + 255) / 256;
    pool_dual<<<pL + pS, 256, 0, stream>>>(A_l, batch_l, NL, A_s, batch_s, NS, psum, pL);
    mlp_kernel<<<512, 128, 0, stream>>>(psum, batch_l, NL, batch_s, NS,
                                        lin1_W, lin1_b, lin2_W, lin2_b,
                                        bn_g, bn_b, out_W, out_b, out);
}

// Round 9
// 767.977 us; speedup vs baseline: 1.1249x; 1.1249x over previous
//
#include <hip/hip_runtime.h>

// ---------------------------------------------------------------------------
// GCN (2-branch) + GAP + MLP head, MI355X.
// R8: keep R7's dual-branch merged launches; REVERT aggregate unroll 8->4
// (R8's 8-deep unroll pushed VGPR 32->68, crossing the 64-VGPR occupancy
// cliff: 69%->28% occupancy, HBM 3.6->2.85 TB/s). Also merge the two
// layer-0 GEMMs into one dual launch. Numerics identical.
// ---------------------------------------------------------------------------

static inline size_t align256(size_t x) { return (x + 255) & ~size_t(255); }

__device__ inline unsigned short f2bf(float f) {  // RNE fp32 -> bf16
    unsigned u = __float_as_uint(f);
    unsigned r = (u + 0x7fffu + ((u >> 16) & 1u)) >> 16;
    return (unsigned short)r;
}
__device__ inline unsigned packbf2(float lo, float hi) {
    return (unsigned)f2bf(lo) | ((unsigned)f2bf(hi) << 16);
}

typedef __attribute__((ext_vector_type(8))) short short8;
typedef __attribute__((ext_vector_type(4))) float floatx4;

#define CHUNK 4096  // edges per block in P0/P2

// ---------------- P0: bucket histogram (bucket = dst>>8), dual ----------------
__global__ __launch_bounds__(256) void bucket_hist_dual(
    const int* __restrict__ dstL, int EL, int NBL, int* __restrict__ bhL,
    const int* __restrict__ dstS, int ES, int NBS, int* __restrict__ bhS, int CL) {
    __shared__ int hist[512];
    int b = blockIdx.x, t = threadIdx.x;
    const int* dst; int E, NB, blk; int* bh;
    if (b < CL) { dst = dstL; E = EL; NB = NBL; bh = bhL; blk = b; }
    else        { dst = dstS; E = ES; NB = NBS; bh = bhS; blk = b - CL; }
    for (int i = t; i < NB; i += 256) hist[i] = 0;
    __syncthreads();
    int base = blk * CHUNK;
    int end = min(E, base + CHUNK);
    for (int e = base + t; e < end; e += 256) atomicAdd(&hist[dst[e] >> 8], 1);
    __syncthreads();
    for (int i = t; i < NB; i += 256) {
        int h = hist[i];
        if (h > 0) atomicAdd(&bh[i], h);
    }
}

// ---------------- P1: scan bucket totals (2 blocks: L then S) ----------------
__global__ __launch_bounds__(256) void scan_buckets_dual(
    const int* __restrict__ bhist, int* __restrict__ bbase, int* __restrict__ bcur,
    int nbL, int* __restrict__ rpL, int NL, int EL,
    int nbS, int* __restrict__ rpS, int NS, int ES) {
    __shared__ int wsum[4];
    int which = blockIdx.x, t = threadIdx.x;
    const int* bh = bhist + which * 512;
    int* bb = bbase + which * 512;
    int* bc = bcur + which * 512;
    int nb = which ? nbS : nbL;
    int* rp = which ? rpS : rpL;
    int N = which ? NS : NL;
    int E = which ? ES : EL;
    int wave = t >> 6, lane = t & 63;
    int i0 = 2 * t, i1 = 2 * t + 1;
    int v0 = (i0 < nb) ? bh[i0] : 0;
    int v1 = (i1 < nb) ? bh[i1] : 0;
    int tsum = v0 + v1;
    int x = tsum;
    #pragma unroll
    for (int off = 1; off < 64; off <<= 1) {
        int y = __shfl_up(x, off, 64);
        if (lane >= off) x += y;
    }
    if (lane == 63) wsum[wave] = x;
    __syncthreads();
    int woff = 0;
    #pragma unroll
    for (int i = 0; i < 3; i++) if (wave > i) woff += wsum[i];
    int texcl = woff + x - tsum;
    if (i0 < nb) { bb[i0] = texcl; bc[i0] = texcl; }
    if (i1 < nb) { bb[i1] = texcl + v0; bc[i1] = texcl + v0; }
    if (t == 255) { bb[nb] = woff + x; rp[N] = E; }
}

// ---------------- P2: partition edges into bucket regions, dual ----------------
__global__ __launch_bounds__(256) void partition_edges_dual(
    const int* __restrict__ srcL, const int* __restrict__ dstL,
    const float* __restrict__ wL, int EL, int NBL, int* __restrict__ bcurL,
    int2* __restrict__ partL,
    const int* __restrict__ srcS, const int* __restrict__ dstS,
    const float* __restrict__ wS, int ES, int NBS, int* __restrict__ bcurS,
    int2* __restrict__ partS, int CL) {
    __shared__ int hist[512];
    __shared__ int lcur[512];
    int b = blockIdx.x, t = threadIdx.x;
    const int *src, *dst; const float* w; int E, NB, blk; int* bcur; int2* part;
    if (b < CL) { src = srcL; dst = dstL; w = wL; E = EL; NB = NBL; bcur = bcurL;
                  part = partL; blk = b; }
    else        { src = srcS; dst = dstS; w = wS; E = ES; NB = NBS; bcur = bcurS;
                  part = partS; blk = b - CL; }
    for (int i = t; i < NB; i += 256) hist[i] = 0;
    __syncthreads();
    int base = blk * CHUNK;
    int end = min(E, base + CHUNK);
    for (int e = base + t; e < end; e += 256) atomicAdd(&hist[dst[e] >> 8], 1);
    __syncthreads();
    for (int i = t; i < NB; i += 256) {
        int h = hist[i];
        if (h > 0) lcur[i] = atomicAdd(&bcur[i], h);
    }
    __syncthreads();
    for (int e = base + t; e < end; e += 256) {
        int d = dst[e];
        int bk = d >> 8;
        int pos = atomicAdd(&lcur[bk], 1);
        part[pos] = make_int2(src[e] | ((d & 255) << 24), __float_as_int(w[e]));
    }
}

// ---------------- P3: per-bucket CSR + rp + dinv, dual ----------------
__global__ __launch_bounds__(256) void bucket_csr_dual(
    const int2* __restrict__ partL, const int* __restrict__ bbaseL, int NL,
    int* __restrict__ rpL, float* __restrict__ dinvL, int2* __restrict__ csrL,
    const int2* __restrict__ partS, const int* __restrict__ bbaseS, int NS,
    int* __restrict__ rpS, float* __restrict__ dinvS, int2* __restrict__ csrS,
    int NBL) {
    __shared__ int hist[256];
    __shared__ float degw[256];
    __shared__ int wsum[4];
    int bb = blockIdx.x, t = threadIdx.x;
    const int2* part; const int* bbase; int N, b; int* rp; float* dinv; int2* csr;
    if (bb < NBL) { part = partL; bbase = bbaseL; N = NL; rp = rpL; dinv = dinvL;
                    csr = csrL; b = bb; }
    else          { part = partS; bbase = bbaseS; N = NS; rp = rpS; dinv = dinvS;
                    csr = csrS; b = bb - NBL; }
    int node0 = b << 8;
    int nn = min(256, N - node0);
    int ebase = bbase[b], eend = bbase[b + 1];
    hist[t] = 0;
    degw[t] = 0.f;
    __syncthreads();
    for (int e = ebase + t; e < eend; e += 256) {
        int2 rec = part[e];
        int nloc = ((unsigned)rec.x) >> 24;
        atomicAdd(&hist[nloc], 1);
        atomicAdd(&degw[nloc], __int_as_float(rec.y));
    }
    __syncthreads();
    int v = hist[t];
    int x = v;
    int wave = t >> 6, lane = t & 63;
    #pragma unroll
    for (int off = 1; off < 64; off <<= 1) {
        int y = __shfl_up(x, off, 64);
        if (lane >= off) x += y;
    }
    if (lane == 63) wsum[wave] = x;
    __syncthreads();
    int woff = 0;
    #pragma unroll
    for (int i = 0; i < 3; i++) if (wave > i) woff += wsum[i];
    int excl = woff + x - v;
    if (t < nn) {
        rp[node0 + t] = ebase + excl;
        dinv[node0 + t] = rsqrtf(1.f + degw[t]);
    }
    hist[t] = excl;
    __syncthreads();
    for (int e = ebase + t; e < eend; e += 256) {
        int2 rec = part[e];
        int nloc = ((unsigned)rec.x) >> 24;
        int pos = ebase + atomicAdd(&hist[nloc], 1);
        csr[pos] = make_int2(rec.x & 0x00FFFFFF, rec.y);
    }
}

// ---------------- layer-0 cast (dual): h~ = bf16(dinv[node] * x) ----------------
template <int F8>
__device__ void cast_body(const float* __restrict__ in, size_t n8,
                          const float* __restrict__ dinv,
                          unsigned short* __restrict__ out, size_t i) {
    if (i >= n8) return;
    float s = dinv[i / F8];
    const float4* in4 = (const float4*)in;
    float4 a = in4[i * 2], b = in4[i * 2 + 1];
    ushort4 lo, hi;
    lo.x = f2bf(a.x * s); lo.y = f2bf(a.y * s); lo.z = f2bf(a.z * s); lo.w = f2bf(a.w * s);
    hi.x = f2bf(b.x * s); hi.y = f2bf(b.y * s); hi.z = f2bf(b.z * s); hi.w = f2bf(b.w * s);
    ushort4* o4 = (ushort4*)out;
    o4[i * 2] = lo;
    o4[i * 2 + 1] = hi;
}

__global__ void cast0_dual(const float* __restrict__ xL, size_t n8L,
                           const float* __restrict__ dinvL, unsigned short* __restrict__ oL,
                           const float* __restrict__ xS, size_t n8S,
                           const float* __restrict__ dinvS, unsigned short* __restrict__ oS,
                           int BL) {
    int b = blockIdx.x;
    if (b < BL) cast_body<8>(xL, n8L, dinvL, oL, (size_t)b * 256 + threadIdx.x);
    else        cast_body<4>(xS, n8S, dinvS, oS, (size_t)(b - BL) * 256 + threadIdx.x);
}

// ---------------- weight cast + transpose ----------------
struct WCastArgs {
    const float* w[8];
    unsigned short* o[8];
    int K[8];
};
__global__ void cast_w16t(WCastArgs p) {
    int mi = blockIdx.y;
    int K = p.K[mi];
    int id = blockIdx.x * 256 + threadIdx.x;
    if (id >= K * 128) return;
    int k = id >> 7, c = id & 127;
    p.o[mi][c * K + k] = f2bf(p.w[mi][k * 128 + c]);
}

// ---------------- aggregation body (4-deep unroll, VGPR<=40) ----------------
// z = bf16( dinv[n] * (sum w*h~[src] + h~[n]) )
template <int LANES>
__device__ void agg_body(const unsigned short* __restrict__ h16, int N,
                         const int* __restrict__ rp, const int2* __restrict__ csr,
                         const float* __restrict__ dinv,
                         unsigned short* __restrict__ z16, int blk) {
    constexpr int GPB = 256 / LANES;
    int group = threadIdx.x / LANES;
    int lane = threadIdx.x % LANES;
    int n = blk * GPB + group;
    if (n >= N) return;
    const uint4* h4 = (const uint4*)h16;
    float acc[8];
    #pragma unroll
    for (int i = 0; i < 8; i++) acc[i] = 0.f;

    int e = rp[n], end = rp[n + 1];
    #define ACC8(q, nm)                                                   \
    {                                                                     \
        acc[0] += nm * __uint_as_float(q.x << 16);                        \
        acc[1] += nm * __uint_as_float(q.x & 0xffff0000u);                \
        acc[2] += nm * __uint_as_float(q.y << 16);                        \
        acc[3] += nm * __uint_as_float(q.y & 0xffff0000u);                \
        acc[4] += nm * __uint_as_float(q.z << 16);                        \
        acc[5] += nm * __uint_as_float(q.z & 0xffff0000u);                \
        acc[6] += nm * __uint_as_float(q.w << 16);                        \
        acc[7] += nm * __uint_as_float(q.w & 0xffff0000u);                \
    }
    for (; e + 3 < end; e += 4) {
        int2 c0 = csr[e], c1 = csr[e + 1], c2 = csr[e + 2], c3 = csr[e + 3];
        uint4 q0 = h4[(size_t)c0.x * LANES + lane];
        uint4 q1 = h4[(size_t)c1.x * LANES + lane];
        uint4 q2 = h4[(size_t)c2.x * LANES + lane];
        uint4 q3 = h4[(size_t)c3.x * LANES + lane];
        float n0 = __int_as_float(c0.y), n1 = __int_as_float(c1.y);
        float n2 = __int_as_float(c2.y), n3 = __int_as_float(c3.y);
        ACC8(q0, n0) ACC8(q1, n1) ACC8(q2, n2) ACC8(q3, n3)
    }
    for (; e < end; e++) {
        int2 c = csr[e];
        uint4 q = h4[(size_t)c.x * LANES + lane];
        float nm = __int_as_float(c.y);
        ACC8(q, nm)
    }
    uint4 qs = h4[(size_t)n * LANES + lane];
    float di = dinv[n];
    float v0 = (acc[0] + __uint_as_float(qs.x << 16)) * di;
    float v1 = (acc[1] + __uint_as_float(qs.x & 0xffff0000u)) * di;
    float v2 = (acc[2] + __uint_as_float(qs.y << 16)) * di;
    float v3 = (acc[3] + __uint_as_float(qs.y & 0xffff0000u)) * di;
    float v4 = (acc[4] + __uint_as_float(qs.z << 16)) * di;
    float v5 = (acc[5] + __uint_as_float(qs.z & 0xffff0000u)) * di;
    float v6 = (acc[6] + __uint_as_float(qs.w << 16)) * di;
    float v7 = (acc[7] + __uint_as_float(qs.w & 0xffff0000u)) * di;
    uint4 o;
    o.x = packbf2(v0, v1); o.y = packbf2(v2, v3);
    o.z = packbf2(v4, v5); o.w = packbf2(v6, v7);
    *(uint4*)&z16[(size_t)n * (LANES * 8) + lane * 8] = o;
    #undef ACC8
}

// layer 1-3: both branches F=128 (LANES=16)
__global__ __launch_bounds__(256) void aggregate_dual(
    const unsigned short* __restrict__ hL, int NL, const int* __restrict__ rpL,
    const int2* __restrict__ csrL, const float* __restrict__ dinvL,
    unsigned short* __restrict__ zL,
    const unsigned short* __restrict__ hS, int NS, const int* __restrict__ rpS,
    const int2* __restrict__ csrS, const float* __restrict__ dinvS,
    unsigned short* __restrict__ zS, int gL) {
    int b = blockIdx.x;
    if (b < gL) agg_body<16>(hL, NL, rpL, csrL, dinvL, zL, b);
    else        agg_body<16>(hS, NS, rpS, csrS, dinvS, zS, b - gL);
}

// layer 0: L F=64 (LANES=8), S F=32 (LANES=4)
__global__ __launch_bounds__(256) void aggregate0_dual(
    const unsigned short* __restrict__ hL, int NL, const int* __restrict__ rpL,
    const int2* __restrict__ csrL, const float* __restrict__ dinvL,
    unsigned short* __restrict__ zL,
    const unsigned short* __restrict__ hS, int NS, const int* __restrict__ rpS,
    const int2* __restrict__ csrS, const float* __restrict__ dinvS,
    unsigned short* __restrict__ zS, int gL) {
    int b = blockIdx.x;
    if (b < gL) agg_body<8>(hL, NL, rpL, csrL, dinvL, zL, b);
    else        agg_body<4>(hS, NS, rpS, csrS, dinvS, zS, b - gL);
}

// ---------------- MFMA GEMM body ----------------
template <int K>
__device__ void gemm_body(const unsigned short* __restrict__ Z16,
                          const unsigned short* __restrict__ WT16,
                          const float* __restrict__ bias, const float* __restrict__ dinv,
                          float* __restrict__ Hf, unsigned short* __restrict__ H16,
                          int N, int blk, unsigned short* WT) {
    constexpr int KP = K + 8;
    int tid = threadIdx.x;
    constexpr int CH = 128 * K / 8;
    for (int i = tid; i < CH; i += 256) {
        int c = i / (K / 8), kc = i % (K / 8);
        *(uint4*)&WT[c * KP + kc * 8] = *(const uint4*)&WT16[c * K + kc * 8];
    }
    __syncthreads();

    int wave = tid >> 6, lane = tid & 63;
    int m = lane & 15, quad = lane >> 4;
    int rowbase = blk * 128 + wave * 32;

    floatx4 acc[2][8];
    #pragma unroll
    for (int t = 0; t < 2; t++)
        #pragma unroll
        for (int ct = 0; ct < 8; ct++) acc[t][ct] = (floatx4)0.f;

    for (int ks = 0; ks < K; ks += 32) {
        short8 a[2];
        #pragma unroll
        for (int t = 0; t < 2; t++) {
            int r = rowbase + t * 16 + m;
            short8 av = (short8)0;
            if (r < N) av = *(const short8*)&Z16[(size_t)r * K + ks + quad * 8];
            a[t] = av;
        }
        #pragma unroll
        for (int ct = 0; ct < 8; ct++) {
            short8 b = *(const short8*)&WT[(ct * 16 + m) * KP + ks + quad * 8];
            acc[0][ct] = __builtin_amdgcn_mfma_f32_16x16x32_bf16(a[0], b, acc[0][ct], 0, 0, 0);
            acc[1][ct] = __builtin_amdgcn_mfma_f32_16x16x32_bf16(a[1], b, acc[1][ct], 0, 0, 0);
        }
    }

    float bv[8];
    #pragma unroll
    for (int ct = 0; ct < 8; ct++) bv[ct] = bias[ct * 16 + m];

    #pragma unroll
    for (int t = 0; t < 2; t++) {
        #pragma unroll
        for (int reg = 0; reg < 4; reg++) {
            int r = rowbase + t * 16 + quad * 4 + reg;
            if (r >= N) continue;
            float di = H16 ? dinv[r] : 1.f;
            #pragma unroll
            for (int ct = 0; ct < 8; ct++) {
                float o = fmaxf(acc[t][ct][reg] + bv[ct], 0.f);
                size_t off = (size_t)r * 128 + ct * 16 + m;
                if (H16) H16[off] = f2bf(o * di);
                if (Hf) Hf[off] = o;
            }
        }
    }
}

// layer 0 dual: L K=64, S K=32 (shared LDS, max footprint 128*72 shorts)
__global__ __launch_bounds__(256) void gemm_mfma_dual0(
    const unsigned short* __restrict__ ZL, const unsigned short* __restrict__ WTL,
    const float* __restrict__ bL, const float* __restrict__ dinvL,
    unsigned short* __restrict__ H16L, int NL,
    const unsigned short* __restrict__ ZS, const unsigned short* __restrict__ WTS,
    const float* __restrict__ bS, const float* __restrict__ dinvS,
    unsigned short* __restrict__ H16S, int NS, int gmL) {
    __shared__ __attribute__((aligned(16))) unsigned short WT[128 * 72];
    int b = blockIdx.x;
    if (b < gmL) gemm_body<64>(ZL, WTL, bL, dinvL, (float*)nullptr, H16L, NL, b, WT);
    else         gemm_body<32>(ZS, WTS, bS, dinvS, (float*)nullptr, H16S, NS, b - gmL, WT);
}

__global__ __launch_bounds__(256) void gemm_mfma_dual128(
    const unsigned short* __restrict__ ZL, const unsigned short* __restrict__ WTL,
    const float* __restrict__ bL, const float* __restrict__ dinvL,
    float* __restrict__ HfL, unsigned short* __restrict__ H16L, int NL,
    const unsigned short* __restrict__ ZS, const unsigned short* __restrict__ WTS,
    const float* __restrict__ bS, const float* __restrict__ dinvS,
    float* __restrict__ HfS, unsigned short* __restrict__ H16S, int NS, int gmL) {
    __shared__ __attribute__((aligned(16))) unsigned short WT[128 * 136];
    int b = blockIdx.x;
    if (b < gmL) gemm_body<128>(ZL, WTL, bL, dinvL, HfL, H16L, NL, b, WT);
    else         gemm_body<128>(ZS, WTS, bS, dinvS, HfS, H16S, NS, b - gmL, WT);
}

// ---------------- pooling (dual): run-length segment accumulation ----------------
__device__ void pool_body(const float* __restrict__ h, const int* __restrict__ batch,
                          int N, float* __restrict__ psum, int blk) {
    int tid = threadIdx.x;
    int f4 = tid & 31;
    int nl = tid >> 5;
    int n0 = blk * 256 + nl;
    const float4* h4 = (const float4*)h;
    float4 acc = make_float4(0.f, 0.f, 0.f, 0.f);
    int cur = -1;
    #pragma unroll 4
    for (int i = 0; i < 32; i++) {
        int n = n0 + i * 8;
        if (n >= N) break;
        int g = batch[n];
        if (g != cur) {
            if (cur >= 0) {
                float* d = &psum[(size_t)cur * 128 + f4 * 4];
                atomicAdd(d + 0, acc.x);
                atomicAdd(d + 1, acc.y);
                atomicAdd(d + 2, acc.z);
                atomicAdd(d + 3, acc.w);
            }
            cur = g;
            acc = make_float4(0.f, 0.f, 0.f, 0.f);
        }
        float4 v = h4[(size_t)n * 32 + f4];
        acc.x += v.x; acc.y += v.y; acc.z += v.z; acc.w += v.w;
    }
    if (cur >= 0) {
        float* d = &psum[(size_t)cur * 128 + f4 * 4];
        atomicAdd(d + 0, acc.x);
        atomicAdd(d + 1, acc.y);
        atomicAdd(d + 2, acc.z);
        atomicAdd(d + 3, acc.w);
    }
}

__global__ __launch_bounds__(256) void pool_dual(
    const float* __restrict__ hL, const int* __restrict__ bL, int NL,
    const float* __restrict__ hS, const int* __restrict__ bS, int NS,
    float* __restrict__ psum, int gL) {
    int b = blockIdx.x;
    if (b < gL) pool_body(hL, bL, NL, psum, b);
    else        pool_body(hS, bS, NS, psum, b - gL);
}

// ---------------- MLP head ----------------
__device__ inline int lower_bound(const int* __restrict__ a, int n, int v) {
    int lo = 0, hi = n;
    while (lo < hi) {
        int m = (lo + hi) >> 1;
        if (a[m] < v) lo = m + 1; else hi = m;
    }
    return lo;
}

__global__ void mlp_kernel(const float* __restrict__ psum,
                           const int* __restrict__ batchL, int NL,
                           const int* __restrict__ batchS, int NS,
                           const float* __restrict__ W1, const float* __restrict__ b1,
                           const float* __restrict__ W2, const float* __restrict__ b2,
                           const float* __restrict__ gamma, const float* __restrict__ beta,
                           const float* __restrict__ outW, const float* __restrict__ outb,
                           float* __restrict__ d_out) {
    __shared__ float row[128];
    __shared__ float row2[128];
    int g = blockIdx.x, t = threadIdx.x;  // 128 threads
    int cnt = (lower_bound(batchL, NL, g + 1) - lower_bound(batchL, NL, g)) +
              (lower_bound(batchS, NS, g + 1) - lower_bound(batchS, NS, g));
    float rcp = 1.f / (float)(cnt > 0 ? cnt : 1);
    row[t] = psum[(size_t)g * 128 + t] * rcp;
    __syncthreads();
    float a = b1[t];
    #pragma unroll 4
    for (int k = 0; k < 128; k++) a += row[k] * W1[k * 128 + t];
    row2[t] = a;  // no relu between lin1 and lin2 in reference
    __syncthreads();
    if (t < 64) {
        float a2 = b2[t];
        #pragma unroll 4
        for (int k = 0; k < 128; k++) a2 += row2[k] * W2[k * 64 + t];
        float rs = rsqrtf(1.0f + 1e-5f);
        float hb = a2 * rs * gamma[t] + beta[t];
        float hr = fmaxf(hb, 0.f);
        d_out[512 + g * 64 + t] = hr;
        float p = hr * outW[t];
        #pragma unroll
        for (int off = 32; off > 0; off >>= 1) p += __shfl_down(p, off, 64);
        if (t == 0) d_out[g] = p + outb[0];
    }
}

// ---------------------------------------------------------------------------
extern "C" void kernel_launch(void* const* d_in, const int* in_sizes, int n_in,
                              void* d_out, int out_size, void* d_ws, size_t ws_size,
                              hipStream_t stream) {
    const float* x_l = (const float*)d_in[0];
    const int*   ei_l = (const int*)d_in[1];
    const float* w_l = (const float*)d_in[2];
    const float* x_s = (const float*)d_in[3];
    const int*   ei_s = (const int*)d_in[4];
    const float* w_s = (const float*)d_in[5];
    const int*   batch_l = (const int*)d_in[6];
    const int*   batch_s = (const int*)d_in[7];

    const int NL = in_sizes[6];           // 100000
    const int NS = in_sizes[7];           // 50000
    const int EL = in_sizes[2];           // 1600000
    const int ES = in_sizes[5];           // 800000

    const float* Wa[4] = {(const float*)d_in[8],  (const float*)d_in[12],
                          (const float*)d_in[16], (const float*)d_in[20]};
    const float* ba[4] = {(const float*)d_in[9],  (const float*)d_in[13],
                          (const float*)d_in[17], (const float*)d_in[21]};
    const float* Wb[4] = {(const float*)d_in[10], (const float*)d_in[14],
                          (const float*)d_in[18], (const float*)d_in[22]};
    const float* bb[4] = {(const float*)d_in[11], (const float*)d_in[15],
                          (const float*)d_in[19], (const float*)d_in[23]};
    const float* lin1_W = (const float*)d_in[24];
    const float* lin1_b = (const float*)d_in[25];
    const float* lin2_W = (const float*)d_in[26];
    const float* lin2_b = (const float*)d_in[27];
    const float* bn_g = (const float*)d_in[28];
    const float* bn_b = (const float*)d_in[29];
    const float* out_W = (const float*)d_in[30];
    const float* out_b = (const float*)d_in[31];
    float* out = (float*)d_out;

    const int* src_l = ei_l;
    const int* dst_l = ei_l + EL;
    const int* src_s = ei_s;
    const int* dst_s = ei_s + ES;

    const int NBL = (NL + 255) >> 8;  // 391
    const int NBS = (NS + 255) >> 8;  // 196
    const int CL = (EL + CHUNK - 1) / CHUNK;
    const int CS = (ES + CHUNK - 1) / CHUNK;

    // ---- workspace carve ----
    char* p = (char*)d_ws;
    auto alloc = [&](size_t bytes) { char* r = p; p += align256(bytes); return r; };
    float* A_l = (float*)alloc((size_t)NL * 128 * 4);   // final-layer fp32 acts
    float* A_s = (float*)alloc((size_t)NS * 128 * 4);
    unsigned short* Z16_l = (unsigned short*)alloc((size_t)NL * 128 * 2);
    unsigned short* Z16_s = (unsigned short*)alloc((size_t)NS * 128 * 2);
    unsigned short* H16_l = (unsigned short*)alloc((size_t)NL * 128 * 2);
    unsigned short* H16_s = (unsigned short*)alloc((size_t)NS * 128 * 2);
    int2*  csr_l  = (int2*)alloc((size_t)EL * 8);
    int2*  csr_s  = (int2*)alloc((size_t)ES * 8);
    int2*  part_l = (int2*)alloc((size_t)EL * 8);
    int2*  part_s = (int2*)alloc((size_t)ES * 8);
    int*   rp_l  = (int*)alloc((size_t)(NL + 1) * 4);
    int*   rp_s  = (int*)alloc((size_t)(NS + 1) * 4);
    float* dinv_l = (float*)alloc((size_t)NL * 4);
    float* dinv_s = (float*)alloc((size_t)NS * 4);
    int*   bhist  = (int*)alloc(1024 * 4);   // [0..511] L, [512..1023] S
    int*   bbase  = (int*)alloc(1024 * 4);
    int*   bcur   = (int*)alloc(1024 * 4);
    float* psum = (float*)alloc((size_t)512 * 128 * 4);
    unsigned short* WTa[4];
    unsigned short* WTb[4];
    WTa[0] = (unsigned short*)alloc((size_t)128 * 64 * 2);
    for (int i = 1; i < 4; i++) WTa[i] = (unsigned short*)alloc((size_t)128 * 128 * 2);
    WTb[0] = (unsigned short*)alloc((size_t)128 * 32 * 2);
    for (int i = 1; i < 4; i++) WTb[i] = (unsigned short*)alloc((size_t)128 * 128 * 2);
    (void)ws_size; (void)n_in; (void)out_size;

    // ---- zero init ----
    hipMemsetAsync(bhist, 0, 1024 * 4, stream);
    hipMemsetAsync(psum, 0, (size_t)512 * 128 * 4, stream);

    // ---- weight cast+transpose ----
    {
        WCastArgs wa;
        for (int i = 0; i < 4; i++) {
            wa.w[i] = Wa[i]; wa.o[i] = WTa[i]; wa.K[i] = (i == 0) ? 64 : 128;
            wa.w[4 + i] = Wb[i]; wa.o[4 + i] = WTb[i]; wa.K[4 + i] = (i == 0) ? 32 : 128;
        }
        cast_w16t<<<dim3(64, 8), 256, 0, stream>>>(wa);
    }

    // ---- CSR build (dual) ----
    bucket_hist_dual<<<CL + CS, 256, 0, stream>>>(dst_l, EL, NBL, bhist,
                                                  dst_s, ES, NBS, bhist + 512, CL);
    scan_buckets_dual<<<2, 256, 0, stream>>>(bhist, bbase, bcur,
                                             NBL, rp_l, NL, EL,
                                             NBS, rp_s, NS, ES);
    partition_edges_dual<<<CL + CS, 256, 0, stream>>>(
        src_l, dst_l, w_l, EL, NBL, bcur, part_l,
        src_s, dst_s, w_s, ES, NBS, bcur + 512, part_s, CL);
    bucket_csr_dual<<<NBL + NBS, 256, 0, stream>>>(
        part_l, bbase, NL, rp_l, dinv_l, csr_l,
        part_s, bbase + 512, NS, rp_s, dinv_s, csr_s, NBL);

    // ---- layer-0 casts (dual) ----
    const size_t n8l = (size_t)NL * 8;   // 64 feats / 8
    const size_t n8s = (size_t)NS * 4;   // 32 feats / 8
    const int cBL = (int)((n8l + 255) / 256);
    const int cBS = (int)((n8s + 255) / 256);
    cast0_dual<<<cBL + cBS, 256, 0, stream>>>(x_l, n8l, dinv_l, H16_l,
                                              x_s, n8s, dinv_s, H16_s, cBL);

    const int gmL = (NL + 127) / 128;
    const int gmS = (NS + 127) / 128;
    const int aL = (NL + 15) / 16;   // LANES=16 blocks
    const int aS = (NS + 15) / 16;
    const int a0L = (NL + 31) / 32;  // LANES=8 blocks
    const int a0S = (NS + 63) / 64;  // LANES=4 blocks

    // ---- layer 0 ----
    aggregate0_dual<<<a0L + a0S, 256, 0, stream>>>(
        H16_l, NL, rp_l, csr_l, dinv_l, Z16_l,
        H16_s, NS, rp_s, csr_s, dinv_s, Z16_s, a0L);
    gemm_mfma_dual0<<<gmL + gmS, 256, 0, stream>>>(
        Z16_l, WTa[0], ba[0], dinv_l, H16_l, NL,
        Z16_s, WTb[0], bb[0], dinv_s, H16_s, NS, gmL);

    // ---- layers 1-3 (dual) ----
    for (int layer = 1; layer < 4; layer++) {
        aggregate_dual<<<aL + aS, 256, 0, stream>>>(
            H16_l, NL, rp_l, csr_l, dinv_l, Z16_l,
            H16_s, NS, rp_s, csr_s, dinv_s, Z16_s, aL);
        if (layer < 3)
            gemm_mfma_dual128<<<gmL + gmS, 256, 0, stream>>>(
                Z16_l, WTa[layer], ba[layer], dinv_l, (float*)nullptr, H16_l, NL,
                Z16_s, WTb[layer], bb[layer], dinv_s, (float*)nullptr, H16_s, NS, gmL);
        else
            gemm_mfma_dual128<<<gmL + gmS, 256, 0, stream>>>(
                Z16_l, WTa[layer], ba[layer], dinv_l, A_l, (unsigned short*)nullptr, NL,
                Z16_s, WTb[layer], bb[layer], dinv_s, A_s, (unsigned short*)nullptr, NS, gmL);
    }

    // ---- pooling + head ----
    const int pL = (NL + 255) / 256;
    const int pS = (NS + 255) / 256;
    pool_dual<<<pL + pS, 256, 0, stream>>>(A_l, batch_l, NL, A_s, batch_s, NS, psum, pL);
    mlp_kernel<<<512, 128, 0, stream>>>(psum, batch_l, NL, batch_s, NS,
                                        lin1_W, lin1_b, lin2_W, lin2_b,
                                        bn_g, bn_b, out_W, out_b, out);
}